// Round 7
// baseline (228.911 us; speedup 1.0000x reference)
//
#include <hip/hip_runtime.h>

// B=8, C=256, H=W=48 -> N=2304, k=4 -> CK=64
#define BATCH 8
#define CIN   256
#define NPIX  2304
#define CKD   64
#define QKLD  128          // qkT row stride (q cols 0-63, k cols 64-127)
#define NJT   (NPIX / 16)  // 144 j-tiles
#define NIC   (NPIX / 32)  // 72 i-chunks
#define KSPL  4
#define ICPS  (NIC / KSPL) // 18 i-chunks per K-split
#define NJB   (NPIX / 64)  // 36 j-blocks (energy partial-sum granularity)

typedef _Float16 f16;
typedef __attribute__((ext_vector_type(4))) _Float16 f16x4;
typedef __attribute__((ext_vector_type(8))) _Float16 f16x8;
typedef __attribute__((ext_vector_type(4))) float    f32x4;

// ---------------------------------------------------------------------------
// Cast all conv weights fp32 -> f16. Wqk = [qw (64x256); kw (64x256)].
// ---------------------------------------------------------------------------
__global__ __launch_bounds__(256) void cast_w(
    const float* __restrict__ qw, const float* __restrict__ kw,
    const float* __restrict__ vw, const float* __restrict__ gw,
    f16* __restrict__ Wqk, f16* __restrict__ Wv, f16* __restrict__ Wg)
{
    int idx = (blockIdx.x * 256 + threadIdx.x) * 4;
    const float* src;
    f16* dst;
    if (idx < 16384)      { src = qw + idx;           dst = Wqk + idx; }
    else if (idx < 32768) { src = kw + (idx - 16384); dst = Wqk + idx; }
    else if (idx < 98304) { src = vw + (idx - 32768); dst = Wv + (idx - 32768); }
    else                  { src = gw + (idx - 98304); dst = Wg + (idx - 98304); }
    float4 v = *(const float4*)src;
    f16x4 h = { (f16)v.x, (f16)v.y, (f16)v.z, (f16)v.w };
    *(f16x4*)dst = h;
}

// ---------------------------------------------------------------------------
// x[b][c][n] fp32 -> xT[b][n][c] f16 (LDS transpose). Tile 64c x 64n.
// ---------------------------------------------------------------------------
__global__ __launch_bounds__(256) void cast_xT(
    const float* __restrict__ x, f16* __restrict__ xT)
{
    __shared__ float s[64][65];
    const int t = threadIdx.x;
    const int n0 = blockIdx.x * 64, c0 = blockIdx.y * 64, b = blockIdx.z;
    const float* xb = x + ((size_t)b * CIN + c0) * NPIX + n0;

    const int cl = t >> 4, ng = (t & 15) * 4;
    #pragma unroll
    for (int p = 0; p < 4; ++p) {
        float4 v = *(const float4*)(xb + (size_t)(cl + 16 * p) * NPIX + ng);
        s[cl + 16 * p][ng + 0] = v.x;
        s[cl + 16 * p][ng + 1] = v.y;
        s[cl + 16 * p][ng + 2] = v.z;
        s[cl + 16 * p][ng + 3] = v.w;
    }
    __syncthreads();
    const int nl = t >> 2, cs = (t & 3) * 16;
    f16 h[16];
    #pragma unroll
    for (int j = 0; j < 16; ++j) h[j] = (f16)s[cs + j][nl];
    f16* gp = &xT[((size_t)b * NPIX + n0 + nl) * CIN + c0 + cs];
    *(f16x8*)gp       = *(f16x8*)&h[0];
    *(f16x8*)(gp + 8) = *(f16x8*)&h[8];
}

// ---------------------------------------------------------------------------
// q & k conv via MFMA: qkT[b][n][o], o<64 = q, o>=64 = k.
// grid (N/32, B), block 256.
// ---------------------------------------------------------------------------
__global__ __launch_bounds__(256) void qk_conv_mfma(
    const f16* __restrict__ xT, const f16* __restrict__ Wqk,
    const float* __restrict__ qbias, const float* __restrict__ kbias,
    f16* __restrict__ qkT)
{
    const int t = threadIdx.x, w = t >> 6, lane = t & 63;
    const int quad = lane >> 4, l16 = lane & 15;
    const int wm = w & 1, wn = w >> 1;
    const int n0 = blockIdx.x * 32, b = blockIdx.y;

    const f16* bp = xT + ((size_t)b * NPIX + n0 + 16 * wn + l16) * CIN;
    const f16* ap = Wqk + (size_t)(64 * wm + l16) * CIN;

    f32x4 acc[4];
    #pragma unroll
    for (int mt = 0; mt < 4; ++mt) acc[mt] = (f32x4){0.f, 0.f, 0.f, 0.f};

    #pragma unroll
    for (int kk = 0; kk < CIN; kk += 32) {
        f16x8 bf = *(const f16x8*)(bp + kk + quad * 8);
        #pragma unroll
        for (int mt = 0; mt < 4; ++mt) {
            f16x8 af = *(const f16x8*)(ap + (size_t)mt * 16 * CIN + kk + quad * 8);
            acc[mt] = __builtin_amdgcn_mfma_f32_16x16x32_f16(af, bf, acc[mt], 0, 0, 0);
        }
    }
    const int n = n0 + 16 * wn + l16;
    const float* bias = wm ? kbias - 64 : qbias;   // o-indexed
    #pragma unroll
    for (int mt = 0; mt < 4; ++mt) {
        int ob = 64 * wm + 16 * mt + quad * 4;
        f16x4 h;
        #pragma unroll
        for (int r = 0; r < 4; ++r)
            h[r] = (f16)(acc[mt][r] + bias[ob + r]);
        *(f16x4*)&qkT[((size_t)b * NPIX + n) * QKLD + ob] = h;
    }
}

// ---------------------------------------------------------------------------
// Energy via MFMA: e[i,j] = exp(q_i . k_j). Tile 64j x 128i.
// Writes Et_blk[b][jt][ic][lane*8] (B-frag-blocked, 1KB/tile, coalesced) and
// per-(i, jblock) partial sums Pred (NO atomics -> no fp32-CAS retry storm).
// grid (N/64 j, N/128 i, B), block 256.
// ---------------------------------------------------------------------------
#define ESL 136   // es row stride in f16 (272B: 16B-aligned, 2-way banks max)
__global__ __launch_bounds__(256) void energy_mfma(
    const f16* __restrict__ qkT, float* __restrict__ Pred,
    f16* __restrict__ Et_blk)
{
    __shared__ __align__(16) f16 es[64 * ESL];
    __shared__ float red2[2][128];
    const int t    = threadIdx.x;
    const int w    = t >> 6, lane = t & 63;
    const int quad = lane >> 4, l16 = lane & 15;
    const int j0 = blockIdx.x * 64, i0 = blockIdx.y * 128, b = blockIdx.z;
    const f16* base = qkT + (size_t)b * NPIX * QKLD;

    f32x4 acc[8];
    #pragma unroll
    for (int mt = 0; mt < 8; ++mt) acc[mt] = (f32x4){0.f, 0.f, 0.f, 0.f};

    #pragma unroll
    for (int ks = 0; ks < 2; ++ks) {
        f16x8 bf = *(const f16x8*)&base[(size_t)(j0 + 16 * w + l16) * QKLD + 64 + ks * 32 + quad * 8];
        #pragma unroll
        for (int mt = 0; mt < 8; ++mt) {
            f16x8 af = *(const f16x8*)&base[(size_t)(i0 + 16 * mt + l16) * QKLD + ks * 32 + quad * 8];
            acc[mt] = __builtin_amdgcn_mfma_f32_16x16x32_f16(af, bf, acc[mt], 0, 0, 0);
        }
    }

    // exp -> LDS tile es[j][i] (lane owns j = 16w+l16, i = 16mt+quad*4+r)
    #pragma unroll
    for (int mt = 0; mt < 8; ++mt) {
        f16x4 h = { (f16)__expf(acc[mt][0]), (f16)__expf(acc[mt][1]),
                    (f16)__expf(acc[mt][2]), (f16)__expf(acc[mt][3]) };
        *(f16x4*)&es[(16 * w + l16) * ESL + 16 * mt + quad * 4] = h;
    }
    __syncthreads();

    // blocked global store: 4jt x 4ic x 64 lanes = 1024 chunks, 4 per thread
    #pragma unroll
    for (int p = 0; p < 4; ++p) {
        int g  = t + 256 * p;
        int jt = g >> 8, ic = (g >> 6) & 3, ln = g & 63;
        f16x8 v = *(const f16x8*)&es[(jt * 16 + (ln & 15)) * ESL + ic * 32 + (ln >> 4) * 8];
        *(f16x8*)&Et_blk[(((size_t)b * NJT + (j0 >> 4) + jt) * NIC + (i0 >> 5) + ic) * 512 + ln * 8] = v;
    }

    // column partial sums over this block's 64 j's
    {
        int i = t & 127, jq = t >> 7;
        float s = 0.f;
        #pragma unroll
        for (int jj = 0; jj < 32; ++jj)
            s += (float)es[(jq * 32 + jj) * ESL + i];
        red2[jq][i] = s;
    }
    __syncthreads();
    if (t < 128) {
        Pred[((size_t)b * NPIX + i0 + t) * NJB + blockIdx.x] =
            red2[0][t] + red2[1][t];
    }
}

// ---------------------------------------------------------------------------
// S[b,i] = sum over 36 j-block partials. 18432 threads.
// ---------------------------------------------------------------------------
__global__ __launch_bounds__(256) void reduce_S(
    const float* __restrict__ Pred, float* __restrict__ S)
{
    int idx = blockIdx.x * 256 + threadIdx.x;
    const float* p = Pred + (size_t)idx * NJB;
    float s = 0.f;
    #pragma unroll
    for (int x = 0; x < NJB; x += 4) {
        float4 v = *(const float4*)(p + x);
        s += v.x + v.y + v.z + v.w;
    }
    S[idx] = s;
}

// ---------------------------------------------------------------------------
// v conv via MFMA, fused bias + 1/S scale; output u in A-frag-blocked layout
// u_blk[b][ct][ic][lane*8] via LDS round-trip (coalesced 16B stores).
// Tile 128(c) x 64(i), BK=32. grid (N/64, C/128, B), block 256.
// ---------------------------------------------------------------------------
__global__ __launch_bounds__(256) void v_conv_mfma(
    const f16* __restrict__ xT, const f16* __restrict__ Wv,
    const float* __restrict__ vbias, const float* __restrict__ S,
    f16* __restrict__ u_blk)
{
    __shared__ __align__(16) f16 smem[9216];   // As 128*40 | Bs 64*40; reused as us 128*72
    f16* As = smem;
    f16* Bs = smem + 128 * 40;
    f16* us = smem;
    const int t = threadIdx.x, w = t >> 6, lane = t & 63;
    const int quad = lane >> 4, l16 = lane & 15;
    const int wm = w & 1, wn = w >> 1;
    const int i0 = blockIdx.x * 64, c0 = blockIdx.y * 128, b = blockIdx.z;
    const int sub = t >> 2, le = t & 3;
    const f16* srcA = Wv + (size_t)(c0 + sub) * CIN + le * 8;
    const f16* srcB = xT + ((size_t)b * NPIX + i0 + sub) * CIN + le * 8;
    const int ldsw = sub * 40 + le * 8;

    f32x4 acc[4][2];
    #pragma unroll
    for (int mt = 0; mt < 4; ++mt)
        #pragma unroll
        for (int nt = 0; nt < 2; ++nt)
            acc[mt][nt] = (f32x4){0.f, 0.f, 0.f, 0.f};

    for (int kk = 0; kk < CIN; kk += 32) {
        f16x8 ta0 = *(const f16x8*)(srcA + kk);
        f16x8 ta1 = *(const f16x8*)(srcA + (size_t)64 * CIN + kk);
        f16x8 tb0 = *(const f16x8*)(srcB + kk);
        __syncthreads();
        *(f16x8*)&As[ldsw]           = ta0;
        *(f16x8*)&As[64 * 40 + ldsw] = ta1;
        *(f16x8*)&Bs[ldsw]           = tb0;
        __syncthreads();
        f16x8 af[4], bf[2];
        #pragma unroll
        for (int mt = 0; mt < 4; ++mt)
            af[mt] = *(const f16x8*)&As[(64 * wm + 16 * mt + l16) * 40 + quad * 8];
        #pragma unroll
        for (int nt = 0; nt < 2; ++nt)
            bf[nt] = *(const f16x8*)&Bs[(32 * wn + 16 * nt + l16) * 40 + quad * 8];
        #pragma unroll
        for (int mt = 0; mt < 4; ++mt)
            #pragma unroll
            for (int nt = 0; nt < 2; ++nt)
                acc[mt][nt] = __builtin_amdgcn_mfma_f32_16x16x32_f16(
                    af[mt], bf[nt], acc[mt][nt], 0, 0, 0);
    }

    __syncthreads();   // As/Bs dead; reuse as us[c][i] (stride 72)
    #pragma unroll
    for (int nt = 0; nt < 2; ++nt) {
        int i = 32 * wn + 16 * nt + l16;
        float is = 1.0f / S[(size_t)b * NPIX + i0 + i];
        #pragma unroll
        for (int mt = 0; mt < 4; ++mt)
            #pragma unroll
            for (int r = 0; r < 4; ++r) {
                int c = 64 * wm + 16 * mt + quad * 4 + r;
                us[c * 72 + i] = (f16)((acc[mt][nt][r] + vbias[c0 + c]) * is);
            }
    }
    __syncthreads();
    // blocked store: 8ct x 2ic x 64 lanes = 1024 chunks, 4 per thread
    #pragma unroll
    for (int p = 0; p < 4; ++p) {
        int g  = t + 256 * p;
        int ct = g >> 7, ic = (g >> 6) & 1, ln = g & 63;
        f16x8 v = *(const f16x8*)&us[(ct * 16 + (ln & 15)) * 72 + ic * 32 + (ln >> 4) * 8];
        *(f16x8*)&u_blk[(((size_t)b * 16 + (c0 >> 4) + ct) * NIC + (i0 >> 5) + ic) * 512 + ln * 8] = v;
    }
}

// ---------------------------------------------------------------------------
// Streaming MFMA bmm (no LDS, no barriers): o1T[b,j,c] = sum_i u[c,i]*E[j,i].
// Frags load directly from blocked layouts as wave-contiguous 1KB dwordx4.
// Block 512 thr = 8 waves (wc=w&3 -> 64c strip, wj=w>>2 -> 64j strip);
// tile 256c x 128j, K-split 4 -> partials p0..p3 (f16, [b][j][c]).
// grid (N/128, KSPL, B).
// ---------------------------------------------------------------------------
__global__ __launch_bounds__(512) void bmm_mfma(
    const f16* __restrict__ u_blk, const f16* __restrict__ Et_blk,
    f16* __restrict__ p0, f16* __restrict__ p1,
    f16* __restrict__ p2, f16* __restrict__ p3)
{
    const int t = threadIdx.x, w = t >> 6, lane = t & 63;
    const int quad = lane >> 4, l16 = lane & 15;
    const int wc = w & 3, wj = w >> 2;
    const int j0 = blockIdx.x * 128;
    const int ks = blockIdx.y, b = blockIdx.z;
    const f16* ub  = u_blk  + (size_t)b * 16 * NIC * 512 + (size_t)lane * 8;
    const f16* ebb = Et_blk + (size_t)b * NJT * NIC * 512 + (size_t)lane * 8;
    f16* outp = (ks == 0) ? p0 : (ks == 1 ? p1 : (ks == 2 ? p2 : p3));
    const int jtb = (j0 >> 4) + wj * 4;

    f32x4 acc[4][4];
    #pragma unroll
    for (int mt = 0; mt < 4; ++mt)
        #pragma unroll
        for (int nt = 0; nt < 4; ++nt)
            acc[mt][nt] = (f32x4){0.f, 0.f, 0.f, 0.f};

    const int ic0 = ks * ICPS;
    #pragma unroll 2
    for (int ic = ic0; ic < ic0 + ICPS; ++ic) {
        f16x8 af[4], bf[4];
        #pragma unroll
        for (int mt = 0; mt < 4; ++mt)
            af[mt] = *(const f16x8*)(ub + (size_t)((wc * 4 + mt) * NIC + ic) * 512);
        #pragma unroll
        for (int nt = 0; nt < 4; ++nt)
            bf[nt] = *(const f16x8*)(ebb + (size_t)((jtb + nt) * NIC + ic) * 512);
        #pragma unroll
        for (int mt = 0; mt < 4; ++mt)
            #pragma unroll
            for (int nt = 0; nt < 4; ++nt)
                acc[mt][nt] = __builtin_amdgcn_mfma_f32_16x16x32_f16(
                    af[mt], bf[nt], acc[mt][nt], 0, 0, 0);
    }

    #pragma unroll
    for (int mt = 0; mt < 4; ++mt) {
        int cb = (wc * 4 + mt) * 16 + quad * 4;
        #pragma unroll
        for (int nt = 0; nt < 4; ++nt) {
            int j = j0 + (wj * 4 + nt) * 16 + l16;
            f16x4 h = { (f16)acc[mt][nt][0], (f16)acc[mt][nt][1],
                        (f16)acc[mt][nt][2], (f16)acc[mt][nt][3] };
            *(f16x4*)&outp[((size_t)b * NPIX + j) * CIN + cb] = h;
        }
    }
}

// ---------------------------------------------------------------------------
// Gamma conv via MFMA: out[b,o,j] = sum_c Wg[o,c]*(p0+p1+p2+p3)[j,c] + gb[o].
// Tile 128(o) x 64(j), BK=32, fp32 out. grid (N/64, C/128, B), block 256.
// ---------------------------------------------------------------------------
__global__ __launch_bounds__(256) void gamma_conv_mfma(
    const f16* __restrict__ p0, const f16* __restrict__ p1,
    const f16* __restrict__ p2, const f16* __restrict__ p3,
    const f16* __restrict__ Wg, const float* __restrict__ gbias,
    float* __restrict__ out)
{
    __shared__ __align__(16) f16 As[128 * 40];
    __shared__ __align__(16) f16 Bs[64 * 40];
    const int t = threadIdx.x, w = t >> 6, lane = t & 63;
    const int quad = lane >> 4, l16 = lane & 15;
    const int wm = w & 1, wn = w >> 1;
    const int j0 = blockIdx.x * 64, o0 = blockIdx.y * 128, b = blockIdx.z;
    const int sub = t >> 2, le = t & 3;
    const f16* srcA  = Wg + (size_t)(o0 + sub) * CIN + le * 8;
    const size_t boff = ((size_t)b * NPIX + j0 + sub) * CIN + le * 8;
    const int ldsw = sub * 40 + le * 8;

    f32x4 acc[4][2];
    #pragma unroll
    for (int mt = 0; mt < 4; ++mt)
        #pragma unroll
        for (int nt = 0; nt < 2; ++nt)
            acc[mt][nt] = (f32x4){0.f, 0.f, 0.f, 0.f};

    for (int kk = 0; kk < CIN; kk += 32) {
        f16x8 ta0 = *(const f16x8*)(srcA + kk);
        f16x8 ta1 = *(const f16x8*)(srcA + (size_t)64 * CIN + kk);
        f16x8 tb0 = *(const f16x8*)(p0 + boff + kk);
        f16x8 tb1 = *(const f16x8*)(p1 + boff + kk);
        f16x8 tb2 = *(const f16x8*)(p2 + boff + kk);
        f16x8 tb3 = *(const f16x8*)(p3 + boff + kk);
        f16x8 tbs = (tb0 + tb1) + (tb2 + tb3);
        __syncthreads();
        *(f16x8*)&As[ldsw]           = ta0;
        *(f16x8*)&As[64 * 40 + ldsw] = ta1;
        *(f16x8*)&Bs[ldsw]           = tbs;
        __syncthreads();
        f16x8 af[4], bf[2];
        #pragma unroll
        for (int mt = 0; mt < 4; ++mt)
            af[mt] = *(const f16x8*)&As[(64 * wm + 16 * mt + l16) * 40 + quad * 8];
        #pragma unroll
        for (int nt = 0; nt < 2; ++nt)
            bf[nt] = *(const f16x8*)&Bs[(32 * wn + 16 * nt + l16) * 40 + quad * 8];
        #pragma unroll
        for (int mt = 0; mt < 4; ++mt)
            #pragma unroll
            for (int nt = 0; nt < 2; ++nt)
                acc[mt][nt] = __builtin_amdgcn_mfma_f32_16x16x32_f16(
                    af[mt], bf[nt], acc[mt][nt], 0, 0, 0);
    }

    #pragma unroll
    for (int mt = 0; mt < 4; ++mt)
        #pragma unroll
        for (int r = 0; r < 4; ++r) {
            int o = o0 + 64 * wm + 16 * mt + quad * 4 + r;
            float bv = gbias[o];
            #pragma unroll
            for (int nt = 0; nt < 2; ++nt) {
                int j = j0 + 32 * wn + 16 * nt + l16;
                out[((size_t)b * CIN + o) * NPIX + j] = acc[mt][nt][r] + bv;
            }
        }
}

// ---------------------------------------------------------------------------
extern "C" void kernel_launch(void* const* d_in, const int* in_sizes, int n_in,
                              void* d_out, int out_size, void* d_ws, size_t ws_size,
                              hipStream_t stream) {
    const float* x   = (const float*)d_in[0];
    const float* qw  = (const float*)d_in[1];
    const float* qbv = (const float*)d_in[2];
    const float* kw  = (const float*)d_in[3];
    const float* kbv = (const float*)d_in[4];
    const float* vw  = (const float*)d_in[5];
    const float* vbv = (const float*)d_in[6];
    const float* gw  = (const float*)d_in[7];
    const float* gbv = (const float*)d_in[8];
    float* out = (float*)d_out;

    const size_t BCN  = (size_t)BATCH * CIN * NPIX;   // 4,718,592
    const size_t BN   = (size_t)BATCH * NPIX;         // 18,432
    const size_t BNN  = (size_t)BATCH * NPIX * NPIX;  // 42,467,328
    const size_t BNQK = (size_t)BATCH * NPIX * QKLD;  // 2,359,296

    // ws layout (~140 MB). xT dead after v_conv; bmm partial p0 reuses it.
    f16* Et    = (f16*)d_ws;          // 84.93 MB (blocked)
    f16* u_blk = Et + BNN;            //  9.44 MB (blocked)
    f16* xT    = u_blk + BCN;         //  9.44 MB (reused as p0)
    f16* qkT   = xT + BCN;            //  4.72 MB
    f16* p1    = qkT + BNQK;          //  9.44 MB
    f16* p2    = p1 + BCN;            //  9.44 MB
    f16* p3    = p2 + BCN;            //  9.44 MB
    f16* Wqk   = p3 + BCN;
    f16* Wv    = Wqk + 128 * 256;
    f16* Wg    = Wv + 256 * 256;
    float* S   = (float*)(Wg + 256 * 256);   // 0.07 MB
    float* Pred= S + BN;                     // 2.65 MB
    f16* p0    = xT;

    cast_w<<<160, 256, 0, stream>>>(qw, kw, vw, gw, Wqk, Wv, Wg);
    cast_xT<<<dim3(NPIX / 64, CIN / 64, BATCH), 256, 0, stream>>>(x, xT);
    qk_conv_mfma<<<dim3(NPIX / 32, BATCH), 256, 0, stream>>>(xT, Wqk, qbv, kbv, qkT);
    energy_mfma<<<dim3(NPIX / 64, NPIX / 128, BATCH), 256, 0, stream>>>(qkT, Pred, Et);
    reduce_S<<<(int)(BN / 256), 256, 0, stream>>>(Pred, S);
    v_conv_mfma<<<dim3(NPIX / 64, CIN / 128, BATCH), 256, 0, stream>>>(xT, Wv, vbv, S, u_blk);
    bmm_mfma<<<dim3(NPIX / 128, KSPL, BATCH), 512, 0, stream>>>(u_blk, Et, p0, p1, p2, p3);
    gamma_conv_mfma<<<dim3(NPIX / 64, CIN / 128, BATCH), 256, 0, stream>>>(p0, p1, p2, p3, Wg, gbv, out);
}

// Round 8
// 207.878 us; speedup vs baseline: 1.1012x; 1.1012x over previous
//
#include <hip/hip_runtime.h>

// B=8, C=256, H=W=48 -> N=2304, k=4 -> CK=64
#define BATCH 8
#define CIN   256
#define NPIX  2304
#define CKD   64
#define NIT   (NPIX / 16)  // 144 16-pixel tiles
#define NIC   (NPIX / 32)  // 72 32-i chunks
#define NJB   (NPIX / 64)  // 36 64-j blocks

typedef _Float16 f16;
typedef __attribute__((ext_vector_type(4))) _Float16 f16x4;
typedef __attribute__((ext_vector_type(8))) _Float16 f16x8;
typedef __attribute__((ext_vector_type(4))) float    f32x4;

// Blocked layouts (tile = 512 f16 = 1KB, lane ln owns bytes ln*8..ln*8+15):
//   q_blk[b][IT][ks][512]  A-frag tiles: pix = IT*16 + (ln&15), ck = ks*32+(ln>>4)*8..
//   k_blk[b][JT][ks][512]  B-frag tiles, same internal structure
//   u_blk[b][CT][ic][512]  A-frag tiles: c = CT*16+(ln&15), i = ic*32+(ln>>4)*8..

// ---------------------------------------------------------------------------
// Cast all conv weights fp32 -> f16. Wqk = [qw (64x256); kw (64x256)].
// ---------------------------------------------------------------------------
__global__ __launch_bounds__(256) void cast_w(
    const float* __restrict__ qw, const float* __restrict__ kw,
    const float* __restrict__ vw, const float* __restrict__ gw,
    f16* __restrict__ Wqk, f16* __restrict__ Wv, f16* __restrict__ Wg)
{
    int idx = (blockIdx.x * 256 + threadIdx.x) * 4;
    const float* src;
    f16* dst;
    if (idx < 16384)      { src = qw + idx;           dst = Wqk + idx; }
    else if (idx < 32768) { src = kw + (idx - 16384); dst = Wqk + idx; }
    else if (idx < 98304) { src = vw + (idx - 32768); dst = Wv + (idx - 32768); }
    else                  { src = gw + (idx - 98304); dst = Wg + (idx - 98304); }
    float4 v = *(const float4*)src;
    f16x4 h = { (f16)v.x, (f16)v.y, (f16)v.z, (f16)v.w };
    *(f16x4*)dst = h;
}

// ---------------------------------------------------------------------------
// x[b][c][n] fp32 -> xT[b][n][c] f16 (LDS transpose). Tile 64c x 64n.
// ---------------------------------------------------------------------------
__global__ __launch_bounds__(256) void cast_xT(
    const float* __restrict__ x, f16* __restrict__ xT)
{
    __shared__ float s[64][65];
    const int t = threadIdx.x;
    const int n0 = blockIdx.x * 64, c0 = blockIdx.y * 64, b = blockIdx.z;
    const float* xb = x + ((size_t)b * CIN + c0) * NPIX + n0;

    const int cl = t >> 4, ng = (t & 15) * 4;
    #pragma unroll
    for (int p = 0; p < 4; ++p) {
        float4 v = *(const float4*)(xb + (size_t)(cl + 16 * p) * NPIX + ng);
        s[cl + 16 * p][ng + 0] = v.x;
        s[cl + 16 * p][ng + 1] = v.y;
        s[cl + 16 * p][ng + 2] = v.z;
        s[cl + 16 * p][ng + 3] = v.w;
    }
    __syncthreads();
    const int nl = t >> 2, cs = (t & 3) * 16;
    f16 h[16];
    #pragma unroll
    for (int j = 0; j < 16; ++j) h[j] = (f16)s[cs + j][nl];
    f16* gp = &xT[((size_t)b * NPIX + n0 + nl) * CIN + c0 + cs];
    *(f16x8*)gp       = *(f16x8*)&h[0];
    *(f16x8*)(gp + 8) = *(f16x8*)&h[8];
}

// ---------------------------------------------------------------------------
// q & k conv via MFMA; outputs q_blk / k_blk (frag-blocked) via LDS repack.
// grid (N/32, B), block 256.
// ---------------------------------------------------------------------------
__global__ __launch_bounds__(256) void qk_conv_mfma(
    const f16* __restrict__ xT, const f16* __restrict__ Wqk,
    const float* __restrict__ qbias, const float* __restrict__ kbias,
    f16* __restrict__ q_blk, f16* __restrict__ k_blk)
{
    __shared__ __align__(16) f16 us[32 * 136];   // [n_local][o], stride 272B
    const int t = threadIdx.x, w = t >> 6, lane = t & 63;
    const int quad = lane >> 4, l16 = lane & 15;
    const int wm = w & 1, wn = w >> 1;
    const int n0 = blockIdx.x * 32, b = blockIdx.y;

    const f16* bp = xT + ((size_t)b * NPIX + n0 + 16 * wn + l16) * CIN;
    const f16* ap = Wqk + (size_t)(64 * wm + l16) * CIN;

    f32x4 acc[4];
    #pragma unroll
    for (int mt = 0; mt < 4; ++mt) acc[mt] = (f32x4){0.f, 0.f, 0.f, 0.f};

    #pragma unroll
    for (int kk = 0; kk < CIN; kk += 32) {
        f16x8 bf = *(const f16x8*)(bp + kk + quad * 8);
        #pragma unroll
        for (int mt = 0; mt < 4; ++mt) {
            f16x8 af = *(const f16x8*)(ap + (size_t)mt * 16 * CIN + kk + quad * 8);
            acc[mt] = __builtin_amdgcn_mfma_f32_16x16x32_f16(af, bf, acc[mt], 0, 0, 0);
        }
    }
    const float* bias = wm ? kbias - 64 : qbias;   // o-indexed
    #pragma unroll
    for (int mt = 0; mt < 4; ++mt) {
        int ob = 64 * wm + 16 * mt + quad * 4;
        #pragma unroll
        for (int r = 0; r < 4; ++r)
            us[(16 * wn + l16) * 136 + ob + r] = (f16)(acc[mt][r] + bias[ob + r]);
    }
    __syncthreads();
    // blocked stores: thread t -> (ks = t>>7, nt = (t>>6)&1, ln = t&63)
    {
        int ks2 = t >> 7, nt = (t >> 6) & 1, ln = t & 63;
        const f16* usr = &us[(nt * 16 + (ln & 15)) * 136 + ks2 * 32 + (ln >> 4) * 8];
        size_t base = (((size_t)b * NIT + (n0 >> 4) + nt) * 2 + ks2) * 512 + ln * 8;
        *(f16x8*)&q_blk[base] = *(const f16x8*)(usr);
        *(f16x8*)&k_blk[base] = *(const f16x8*)(usr + 64);
    }
}

// ---------------------------------------------------------------------------
// S-only energy pass: partial row sums of f16(exp(q_i.k_j)) per 64-j block.
// Blocked (contiguous) frag loads; no Et store. grid (N/64 j, N/128 i, B).
// ---------------------------------------------------------------------------
#define ESL 136
__global__ __launch_bounds__(256) void energy_S(
    const f16* __restrict__ q_blk, const f16* __restrict__ k_blk,
    float* __restrict__ Pred)
{
    __shared__ __align__(16) f16 es[64 * ESL];
    __shared__ float red2[2][128];
    const int t    = threadIdx.x;
    const int w    = t >> 6, lane = t & 63;
    const int quad = lane >> 4, l16 = lane & 15;
    const int j0 = blockIdx.x * 64, i0 = blockIdx.y * 128, b = blockIdx.z;
    const size_t ln8 = (size_t)lane * 8;
    const f16* qb = q_blk + (size_t)b * NIT * 2 * 512 + ln8;

    f32x4 acc[8];
    #pragma unroll
    for (int mt = 0; mt < 8; ++mt) acc[mt] = (f32x4){0.f, 0.f, 0.f, 0.f};

    #pragma unroll
    for (int ks = 0; ks < 2; ++ks) {
        f16x8 bf = *(const f16x8*)(k_blk +
            (((size_t)b * NIT + (j0 >> 4) + w) * 2 + ks) * 512 + ln8);
        #pragma unroll
        for (int mt = 0; mt < 8; ++mt) {
            f16x8 af = *(const f16x8*)(qb + ((size_t)((i0 >> 4) + mt) * 2 + ks) * 512);
            acc[mt] = __builtin_amdgcn_mfma_f32_16x16x32_f16(af, bf, acc[mt], 0, 0, 0);
        }
    }

    // exp -> LDS es[j][i] (lane: j = 16w+l16, i = 16mt+quad*4+r)
    #pragma unroll
    for (int mt = 0; mt < 8; ++mt) {
        f16x4 h = { (f16)__expf(acc[mt][0]), (f16)__expf(acc[mt][1]),
                    (f16)__expf(acc[mt][2]), (f16)__expf(acc[mt][3]) };
        *(f16x4*)&es[(16 * w + l16) * ESL + 16 * mt + quad * 4] = h;
    }
    __syncthreads();
    {
        int i = t & 127, jq = t >> 7;
        float s = 0.f;
        #pragma unroll
        for (int jj = 0; jj < 32; ++jj)
            s += (float)es[(jq * 32 + jj) * ESL + i];
        red2[jq][i] = s;
    }
    __syncthreads();
    if (t < 128)
        Pred[((size_t)blockIdx.x * BATCH + b) * NPIX + i0 + t] =
            red2[0][t] + red2[1][t];
}

// ---------------------------------------------------------------------------
// S[b,i] = sum over 36 j-block partials (coalesced). grid BN/256.
// ---------------------------------------------------------------------------
__global__ __launch_bounds__(256) void reduce_S(
    const float* __restrict__ Pred, float* __restrict__ S)
{
    const size_t BN = (size_t)BATCH * NPIX;
    size_t idx = (size_t)blockIdx.x * 256 + threadIdx.x;
    float s = 0.f;
    #pragma unroll
    for (int jb = 0; jb < NJB; ++jb)
        s += Pred[(size_t)jb * BN + idx];
    S[idx] = s;
}

// ---------------------------------------------------------------------------
// v conv via MFMA, fused bias + 1/S scale; output u_blk (A-frag-blocked).
// Tile 128(c) x 64(i), BK=32. grid (N/64, C/128, B), block 256.
// ---------------------------------------------------------------------------
__global__ __launch_bounds__(256) void v_conv_mfma(
    const f16* __restrict__ xT, const f16* __restrict__ Wv,
    const float* __restrict__ vbias, const float* __restrict__ S,
    f16* __restrict__ u_blk)
{
    __shared__ __align__(16) f16 smem[9216];   // As 128*40 | Bs 64*40; reused as us 128*72
    f16* As = smem;
    f16* Bs = smem + 128 * 40;
    f16* us = smem;
    const int t = threadIdx.x, w = t >> 6, lane = t & 63;
    const int quad = lane >> 4, l16 = lane & 15;
    const int wm = w & 1, wn = w >> 1;
    const int i0 = blockIdx.x * 64, c0 = blockIdx.y * 128, b = blockIdx.z;
    const int sub = t >> 2, le = t & 3;
    const f16* srcA = Wv + (size_t)(c0 + sub) * CIN + le * 8;
    const f16* srcB = xT + ((size_t)b * NPIX + i0 + sub) * CIN + le * 8;
    const int ldsw = sub * 40 + le * 8;

    f32x4 acc[4][2];
    #pragma unroll
    for (int mt = 0; mt < 4; ++mt)
        #pragma unroll
        for (int nt = 0; nt < 2; ++nt)
            acc[mt][nt] = (f32x4){0.f, 0.f, 0.f, 0.f};

    for (int kk = 0; kk < CIN; kk += 32) {
        f16x8 ta0 = *(const f16x8*)(srcA + kk);
        f16x8 ta1 = *(const f16x8*)(srcA + (size_t)64 * CIN + kk);
        f16x8 tb0 = *(const f16x8*)(srcB + kk);
        __syncthreads();
        *(f16x8*)&As[ldsw]           = ta0;
        *(f16x8*)&As[64 * 40 + ldsw] = ta1;
        *(f16x8*)&Bs[ldsw]           = tb0;
        __syncthreads();
        f16x8 af[4], bf[2];
        #pragma unroll
        for (int mt = 0; mt < 4; ++mt)
            af[mt] = *(const f16x8*)&As[(64 * wm + 16 * mt + l16) * 40 + quad * 8];
        #pragma unroll
        for (int nt = 0; nt < 2; ++nt)
            bf[nt] = *(const f16x8*)&Bs[(32 * wn + 16 * nt + l16) * 40 + quad * 8];
        #pragma unroll
        for (int mt = 0; mt < 4; ++mt)
            #pragma unroll
            for (int nt = 0; nt < 2; ++nt)
                acc[mt][nt] = __builtin_amdgcn_mfma_f32_16x16x32_f16(
                    af[mt], bf[nt], acc[mt][nt], 0, 0, 0);
    }

    __syncthreads();   // As/Bs dead; reuse as us[c][i] (stride 72)
    #pragma unroll
    for (int nt = 0; nt < 2; ++nt) {
        int i = 32 * wn + 16 * nt + l16;
        float is = 1.0f / S[(size_t)b * NPIX + i0 + i];
        #pragma unroll
        for (int mt = 0; mt < 4; ++mt)
            #pragma unroll
            for (int r = 0; r < 4; ++r) {
                int c = 64 * wm + 16 * mt + quad * 4 + r;
                us[c * 72 + i] = (f16)((acc[mt][nt][r] + vbias[c0 + c]) * is);
            }
    }
    __syncthreads();
    #pragma unroll
    for (int p = 0; p < 4; ++p) {
        int g  = t + 256 * p;
        int ct = g >> 7, ic = (g >> 6) & 1, ln = g & 63;
        f16x8 v = *(const f16x8*)&us[(ct * 16 + (ln & 15)) * 72 + ic * 32 + (ln >> 4) * 8];
        *(f16x8*)&u_blk[(((size_t)b * 16 + (c0 >> 4) + ct) * NIC + (i0 >> 5) + ic) * 512 + ln * 8] = v;
    }
}

// ---------------------------------------------------------------------------
// FUSED bmm: o1T[b,j,c] = sum_i u[c,i] * f16(exp(q_i.k_j))
// Block 64j x 128c, 4 waves. k-frags resident in regs; per 64-i chunk:
//  stage1 (8 MFMA): E-tile 64i x 16j (jt=w) from blocked q/k -> exp -> es LDS
//  stage2 (16 MFMA): acc += u_blk frags x es B-frags
// All global frag loads are wave-contiguous 1KB. grid (36, 2, 8).
// ---------------------------------------------------------------------------
__global__ __launch_bounds__(256) void fused_bmm(
    const f16* __restrict__ q_blk, const f16* __restrict__ k_blk,
    const f16* __restrict__ u_blk, f16* __restrict__ o1T)
{
    __shared__ __align__(16) f16 es[64 * 72];   // [j][i], 144B rows
    const int t = threadIdx.x, w = t >> 6, lane = t & 63;
    const int quad = lane >> 4, l16 = lane & 15;
    const int j0 = blockIdx.x * 64;
    const int ch = blockIdx.y, b = blockIdx.z;
    const size_t ln8 = (size_t)lane * 8;

    const f16* qb = q_blk + (size_t)b * NIT * 2 * 512 + ln8;
    const f16* ub = u_blk + (size_t)b * 16 * NIC * 512 + ln8;

    // k-frags for this wave's j-strip (jt = w), resident for whole kernel
    f16x8 kf[2];
    #pragma unroll
    for (int ks = 0; ks < 2; ++ks)
        kf[ks] = *(const f16x8*)(k_blk +
            (((size_t)b * NIT + (j0 >> 4) + w) * 2 + ks) * 512 + ln8);

    const int CT0 = ch * 8 + 2 * w;   // this wave's two u c-tiles

    f32x4 acc[2][4];
    #pragma unroll
    for (int mt = 0; mt < 2; ++mt)
        #pragma unroll
        for (int jt = 0; jt < 4; ++jt)
            acc[mt][jt] = (f32x4){0.f, 0.f, 0.f, 0.f};

    for (int ic = 0; ic < NPIX / 64; ++ic) {
        // ---- stage 1: E (64 i) x (16 j, jt = w)
        f32x4 e[4];
        #pragma unroll
        for (int it = 0; it < 4; ++it) e[it] = (f32x4){0.f, 0.f, 0.f, 0.f};
        #pragma unroll
        for (int ks = 0; ks < 2; ++ks)
            #pragma unroll
            for (int it = 0; it < 4; ++it) {
                f16x8 af = *(const f16x8*)(qb + ((size_t)(ic * 4 + it) * 2 + ks) * 512);
                e[it] = __builtin_amdgcn_mfma_f32_16x16x32_f16(af, kf[ks], e[it], 0, 0, 0);
            }
        __syncthreads();   // prior stage-2 reads of es complete
        #pragma unroll
        for (int it = 0; it < 4; ++it) {
            f16x4 h = { (f16)__expf(e[it][0]), (f16)__expf(e[it][1]),
                        (f16)__expf(e[it][2]), (f16)__expf(e[it][3]) };
            *(f16x4*)&es[(16 * w + l16) * 72 + it * 16 + quad * 4] = h;
        }
        __syncthreads();
        // ---- stage 2
        #pragma unroll
        for (int isub = 0; isub < 2; ++isub) {
            f16x8 af0 = *(const f16x8*)(ub + ((size_t)(CT0 + 0) * NIC + ic * 2 + isub) * 512);
            f16x8 af1 = *(const f16x8*)(ub + ((size_t)(CT0 + 1) * NIC + ic * 2 + isub) * 512);
            #pragma unroll
            for (int jt = 0; jt < 4; ++jt) {
                f16x8 bf = *(const f16x8*)&es[(16 * jt + l16) * 72 + isub * 32 + quad * 8];
                acc[0][jt] = __builtin_amdgcn_mfma_f32_16x16x32_f16(af0, bf, acc[0][jt], 0, 0, 0);
                acc[1][jt] = __builtin_amdgcn_mfma_f32_16x16x32_f16(af1, bf, acc[1][jt], 0, 0, 0);
            }
        }
    }

    #pragma unroll
    for (int mt = 0; mt < 2; ++mt) {
        int cb = ch * 128 + 32 * w + 16 * mt + quad * 4;
        #pragma unroll
        for (int jt = 0; jt < 4; ++jt) {
            int j = j0 + 16 * jt + l16;
            f16x4 h = { (f16)acc[mt][jt][0], (f16)acc[mt][jt][1],
                        (f16)acc[mt][jt][2], (f16)acc[mt][jt][3] };
            *(f16x4*)&o1T[((size_t)b * NPIX + j) * CIN + cb] = h;
        }
    }
}

// ---------------------------------------------------------------------------
// Gamma conv via MFMA: out[b,o,j] = sum_c Wg[o,c]*o1[c,j] + gb[o], fp32 out.
// Tile 128(o) x 64(j), BK=32. grid (N/64, C/128, B), block 256.
// ---------------------------------------------------------------------------
__global__ __launch_bounds__(256) void gamma_conv_mfma(
    const f16* __restrict__ o1T, const f16* __restrict__ Wg,
    const float* __restrict__ gbias, float* __restrict__ out)
{
    __shared__ __align__(16) f16 As[128 * 40];
    __shared__ __align__(16) f16 Bs[64 * 40];
    const int t = threadIdx.x, w = t >> 6, lane = t & 63;
    const int quad = lane >> 4, l16 = lane & 15;
    const int wm = w & 1, wn = w >> 1;
    const int j0 = blockIdx.x * 64, o0 = blockIdx.y * 128, b = blockIdx.z;
    const int sub = t >> 2, le = t & 3;
    const f16* srcA = Wg + (size_t)(o0 + sub) * CIN + le * 8;
    const f16* srcB = o1T + ((size_t)b * NPIX + j0 + sub) * CIN + le * 8;
    const int ldsw = sub * 40 + le * 8;

    f32x4 acc[4][2];
    #pragma unroll
    for (int mt = 0; mt < 4; ++mt)
        #pragma unroll
        for (int nt = 0; nt < 2; ++nt)
            acc[mt][nt] = (f32x4){0.f, 0.f, 0.f, 0.f};

    for (int kk = 0; kk < CIN; kk += 32) {
        f16x8 ta0 = *(const f16x8*)(srcA + kk);
        f16x8 ta1 = *(const f16x8*)(srcA + (size_t)64 * CIN + kk);
        f16x8 tb0 = *(const f16x8*)(srcB + kk);
        __syncthreads();
        *(f16x8*)&As[ldsw]           = ta0;
        *(f16x8*)&As[64 * 40 + ldsw] = ta1;
        *(f16x8*)&Bs[ldsw]           = tb0;
        __syncthreads();
        f16x8 af[4], bf[2];
        #pragma unroll
        for (int mt = 0; mt < 4; ++mt)
            af[mt] = *(const f16x8*)&As[(64 * wm + 16 * mt + l16) * 40 + quad * 8];
        #pragma unroll
        for (int nt = 0; nt < 2; ++nt)
            bf[nt] = *(const f16x8*)&Bs[(32 * wn + 16 * nt + l16) * 40 + quad * 8];
        #pragma unroll
        for (int mt = 0; mt < 4; ++mt)
            #pragma unroll
            for (int nt = 0; nt < 2; ++nt)
                acc[mt][nt] = __builtin_amdgcn_mfma_f32_16x16x32_f16(
                    af[mt], bf[nt], acc[mt][nt], 0, 0, 0);
    }

    #pragma unroll
    for (int mt = 0; mt < 4; ++mt)
        #pragma unroll
        for (int r = 0; r < 4; ++r) {
            int o = o0 + 64 * wm + 16 * mt + quad * 4 + r;
            float bv = gbias[o];
            #pragma unroll
            for (int nt = 0; nt < 2; ++nt) {
                int j = j0 + 32 * wn + 16 * nt + l16;
                out[((size_t)b * CIN + o) * NPIX + j] = acc[mt][nt][r] + bv;
            }
        }
}

// ---------------------------------------------------------------------------
extern "C" void kernel_launch(void* const* d_in, const int* in_sizes, int n_in,
                              void* d_out, int out_size, void* d_ws, size_t ws_size,
                              hipStream_t stream) {
    const float* x   = (const float*)d_in[0];
    const float* qw  = (const float*)d_in[1];
    const float* qbv = (const float*)d_in[2];
    const float* kw  = (const float*)d_in[3];
    const float* kbv = (const float*)d_in[4];
    const float* vw  = (const float*)d_in[5];
    const float* vbv = (const float*)d_in[6];
    const float* gw  = (const float*)d_in[7];
    const float* gbv = (const float*)d_in[8];
    float* out = (float*)d_out;

    const size_t BCN  = (size_t)BATCH * CIN * NPIX;   // 4,718,592
    const size_t BN   = (size_t)BATCH * NPIX;         // 18,432
    const size_t BNCK = (size_t)BATCH * NPIX * CKD;   // 1,179,648

    // ws layout (~36 MB)
    f16* q_blk = (f16*)d_ws;          // 2.36 MB
    f16* k_blk = q_blk + BNCK;        // 2.36 MB
    f16* u_blk = k_blk + BNCK;        // 9.44 MB
    f16* xT    = u_blk + BCN;         // 9.44 MB
    f16* o1T   = xT + BCN;            // 9.44 MB
    f16* Wqk   = o1T + BCN;
    f16* Wv    = Wqk + 128 * 256;
    f16* Wg    = Wv + 256 * 256;
    float* S   = (float*)(Wg + 256 * 256);   // 0.07 MB
    float* Pred= S + BN;                      // 2.65 MB

    cast_w<<<160, 256, 0, stream>>>(qw, kw, vw, gw, Wqk, Wv, Wg);
    cast_xT<<<dim3(NPIX / 64, CIN / 64, BATCH), 256, 0, stream>>>(x, xT);
    qk_conv_mfma<<<dim3(NPIX / 32, BATCH), 256, 0, stream>>>(xT, Wqk, qbv, kbv, q_blk, k_blk);
    energy_S<<<dim3(NPIX / 64, NPIX / 128, BATCH), 256, 0, stream>>>(q_blk, k_blk, Pred);
    reduce_S<<<(int)(BN / 256), 256, 0, stream>>>(Pred, S);
    v_conv_mfma<<<dim3(NPIX / 64, CIN / 128, BATCH), 256, 0, stream>>>(xT, Wv, vbv, S, u_blk);
    fused_bmm<<<dim3(NPIX / 64, 2, BATCH), 256, 0, stream>>>(q_blk, k_blk, u_blk, o1T);
    gamma_conv_mfma<<<dim3(NPIX / 64, CIN / 128, BATCH), 256, 0, stream>>>(o1T, Wg, gbv, out);
}